// Round 5
// baseline (398.586 us; speedup 1.0000x reference)
//
#include <hip/hip_runtime.h>
#include <math.h>

#define KC 24
constexpr int D = 16;
constexpr int B = 4;
constexpr int N = 512 * 1024;          // points per image, 2^19
constexpr float DELTA_VAR = 1.0f;
constexpr float DELTA_DIST = 2.0f;

constexpr int REP = 8;                 // LDS accumulator replicas (replica = t&7)
constexpr int RS  = KC * 17;           // 408 words per sum replica
constexpr int CS  = 33;
constexpr int TPB = 512;
constexpr int PTS = 8192;              // points per block
constexpr int NBLK = (B * N) / PTS;    // 256 blocks; 147KB LDS forces 1 block/CU -> all resident
constexpr int SL = 8;                  // global accumulator slices
constexpr int RLDS = 4;                // planes 0..3 retained in LDS (128 KB)
constexpr int RREG = 12;               // planes 4..15 retained in VGPRs (192 regs)
constexpr int WS_FLOATS = SL * (B * KC * D) + SL * (B * KC) + 64;  // 13120

// ws: g_sums [SL][B*KC*D] | g_cnt [SL][B*KC] | g_varp [64] | barrier {cnt,gen}

__device__ __forceinline__ float gldf(const float* p) {
    return __hip_atomic_load(p, __ATOMIC_RELAXED, __HIP_MEMORY_SCOPE_AGENT);
}

// sense-reversing grid barrier; bounded spin so a residency failure fails visibly, not hangs
__device__ __forceinline__ void gsync(int* cnt, int* gen) {
    __syncthreads();
    if (threadIdx.x == 0) {
        int g = __hip_atomic_load(gen, __ATOMIC_ACQUIRE, __HIP_MEMORY_SCOPE_AGENT);
        if (__hip_atomic_fetch_add(cnt, 1, __ATOMIC_ACQ_REL, __HIP_MEMORY_SCOPE_AGENT) == NBLK - 1) {
            __hip_atomic_store(cnt, 0, __ATOMIC_RELAXED, __HIP_MEMORY_SCOPE_AGENT);
            __hip_atomic_fetch_add(gen, 1, __ATOMIC_ACQ_REL, __HIP_MEMORY_SCOPE_AGENT);
        } else {
            for (int it = 0; it < (1 << 24); ++it) {
                if (__hip_atomic_load(gen, __ATOMIC_ACQUIRE, __HIP_MEMORY_SCOPE_AGENT) != g) break;
                __builtin_amdgcn_s_sleep(2);
            }
        }
    }
    __syncthreads();
}

// keep a float4 pinned in VGPRs (blocks load rematerialization across the barrier)
#define KEEP4(f4) asm volatile("" : "+v"((f4).x), "+v"((f4).y), "+v"((f4).z), "+v"((f4).w))

__global__ __launch_bounds__(TPB) void k_fused(const float* __restrict__ data,
                                               const int* __restrict__ labels,
                                               float* __restrict__ ws,
                                               float* __restrict__ out) {
    __shared__ float s_sum[REP * RS];                        // 13056 B
    __shared__ float s_cnt[REP * CS];                        // 1056 B
    __shared__ __align__(16) float4 s_data4[RLDS][PTS / 4];  // 131072 B
    __shared__ float s_c[KC * 17];                           // 1632 B
    __shared__ float s_ic[KC];
    __shared__ float s_red[8];

    float* g_sums = ws;
    float* g_cnt  = ws + SL * (B * KC * D);
    float* g_varp = g_cnt + SL * (B * KC);
    int*   bar    = (int*)(g_varp + 64);

    const int t = threadIdx.x;
    const int chunk = blockIdx.x * PTS;
    const int b = chunk >> 19;
    const float* base = data + (size_t)(b * D) * N + (chunk & (N - 1));

    // early global loads (labels + plane 0) overlap the LDS zeroing
    int4 lab[4];
#pragma unroll
    for (int i = 0; i < 4; ++i)
        lab[i] = *(const int4*)(labels + chunk + (i * TPB + t) * 4);

    float4 tmp[2][4];
#pragma unroll
    for (int i = 0; i < 4; ++i)
        tmp[0][i] = *(const float4*)(base + (i * TPB + t) * 4);

    for (int i = t; i < REP * RS; i += TPB) s_sum[i] = 0.f;
    for (int i = t; i < REP * CS; i += TPB) s_cnt[i] = 0.f;
    __syncthreads();

    const int rbase = (t & 7) * RS;
    const int cbase = (t & 7) * CS;
#pragma unroll
    for (int i = 0; i < 4; ++i) {
        atomicAdd(&s_cnt[cbase + lab[i].x], 1.f);
        atomicAdd(&s_cnt[cbase + lab[i].y], 1.f);
        atomicAdd(&s_cnt[cbase + lab[i].z], 1.f);
        atomicAdd(&s_cnt[cbase + lab[i].w], 1.f);
    }

    // ---- phase 1: planes 0..3 -> LDS (low reg pressure), planes 4..15 -> vr ----
    float4 vr[RREG][4];
#pragma unroll
    for (int d = 0; d < D; ++d) {
        if (d + 1 < D) {
#pragma unroll
            for (int i = 0; i < 4; ++i) {
                float4 nx = *(const float4*)(base + (size_t)(d + 1) * N + (i * TPB + t) * 4);
                if (d + 1 < RLDS) tmp[(d + 1) & 1][i] = nx;
                else              vr[d + 1 - RLDS][i] = nx;
            }
        }
#pragma unroll
        for (int i = 0; i < 4; ++i) {
            const float4 c = (d < RLDS) ? tmp[d & 1][i] : vr[d - RLDS][i];
            if (d < RLDS) s_data4[d][i * TPB + t] = c;
            atomicAdd(&s_sum[rbase + lab[i].x * 17 + d], c.x);
            atomicAdd(&s_sum[rbase + lab[i].y * 17 + d], c.y);
            atomicAdd(&s_sum[rbase + lab[i].z * 17 + d], c.z);
            atomicAdd(&s_sum[rbase + lab[i].w * 17 + d], c.w);
        }
    }

    // pin retained planes in registers: compiler cannot re-load them in phase 2
#pragma unroll
    for (int d = 0; d < RREG; ++d)
#pragma unroll
        for (int i = 0; i < 4; ++i) KEEP4(vr[d][i]);

    __syncthreads();

    // epilogue: rotated order + per-slice targets
    const int slice = blockIdx.x & (SL - 1);
    float* gs = g_sums + slice * (B * KC * D) + b * (KC * D);
    float* gc = g_cnt  + slice * (B * KC)     + b * KC;
    const int rot = (blockIdx.x * 131) & 255;
    for (int i = t; i < KC * D; i += TPB) {
        int j = (i + rot) % (KC * D);
        int c = j >> 4, dd = j & 15;
        float s = 0.f;
#pragma unroll
        for (int r = 0; r < REP; ++r) s += s_sum[r * RS + c * 17 + dd];
        atomicAdd(&gs[j], s);
    }
    if (t < KC) {
        float s = 0.f;
#pragma unroll
        for (int r = 0; r < REP; ++r) s += s_cnt[r * CS + t];
        atomicAdd(&gc[t], s);
    }

    gsync(bar, bar + 1);   // sums + counts final

    // ---- phase 2: centers + hinged variance (ZERO global data loads) ----
    if (t < KC) {
        float cn = 0.f;
#pragma unroll
        for (int r = 0; r < SL; ++r) cn += gldf(&g_cnt[r * (B * KC) + b * KC + t]);
        s_ic[t] = 1.f / cn;
    }
    __syncthreads();
    for (int i = t; i < KC * D; i += TPB) {
        int c = i >> 4, dd = i & 15;
        float s = 0.f;
#pragma unroll
        for (int r = 0; r < SL; ++r) s += gldf(&g_sums[r * (B * KC * D) + b * (KC * D) + i]);
        s_c[c * 17 + dd] = s * s_ic[c];
    }
    __syncthreads();

    float ac[16];
#pragma unroll
    for (int i = 0; i < 16; ++i) ac[i] = 0.f;

#pragma unroll
    for (int p = 0; p < RLDS; ++p) {   // LDS planes: d = 0..3
        const int d = p;
#pragma unroll
        for (int i = 0; i < 4; ++i) {
            const float4 c = s_data4[p][i * TPB + t];
            float df;
            df = c.x - s_c[lab[i].x * 17 + d]; ac[i * 4 + 0] += df * df;
            df = c.y - s_c[lab[i].y * 17 + d]; ac[i * 4 + 1] += df * df;
            df = c.z - s_c[lab[i].z * 17 + d]; ac[i * 4 + 2] += df * df;
            df = c.w - s_c[lab[i].w * 17 + d]; ac[i * 4 + 3] += df * df;
        }
    }
#pragma unroll
    for (int rr = 0; rr < RREG; ++rr) { // register planes: d = 4..15
        const int d = RLDS + rr;
#pragma unroll
        for (int i = 0; i < 4; ++i) {
            const float4 c = vr[rr][i];
            float df;
            df = c.x - s_c[lab[i].x * 17 + d]; ac[i * 4 + 0] += df * df;
            df = c.y - s_c[lab[i].y * 17 + d]; ac[i * 4 + 1] += df * df;
            df = c.z - s_c[lab[i].z * 17 + d]; ac[i * 4 + 2] += df * df;
            df = c.w - s_c[lab[i].w * 17 + d]; ac[i * 4 + 3] += df * df;
        }
    }

    float hsum = 0.f;
#pragma unroll
    for (int i = 0; i < 4; ++i) {
        float h;
        h = fmaxf(sqrtf(ac[i * 4 + 0]) - DELTA_VAR, 0.f); hsum += h * h * s_ic[lab[i].x];
        h = fmaxf(sqrtf(ac[i * 4 + 1]) - DELTA_VAR, 0.f); hsum += h * h * s_ic[lab[i].y];
        h = fmaxf(sqrtf(ac[i * 4 + 2]) - DELTA_VAR, 0.f); hsum += h * h * s_ic[lab[i].z];
        h = fmaxf(sqrtf(ac[i * 4 + 3]) - DELTA_VAR, 0.f); hsum += h * h * s_ic[lab[i].w];
    }
    for (int o = 32; o > 0; o >>= 1) hsum += __shfl_down(hsum, o, 64);
    if ((t & 63) == 0) s_red[t >> 6] = hsum;
    __syncthreads();
    if (t == 0) {
        float s = 0.f;
#pragma unroll
        for (int w = 0; w < 8; ++w) s += s_red[w];
        atomicAdd(&g_varp[blockIdx.x & 63], s);
    }

    gsync(bar, bar + 1);   // varp final

    if (blockIdx.x != 0) return;

    // ---- finalize (block 0): var + dist + reg -> scalar ----
    float* s_cF = (float*)&s_data4[0][0];   // reuse 128 KB region; needs 6528 floats
    float acc = 0.f;
    if (t < B * KC) {
        float cnt = 0.f;
#pragma unroll
        for (int r = 0; r < SL; ++r) cnt += gldf(&g_cnt[r * (B * KC) + t]);
        float ns = 0.f;
        for (int dd = 0; dd < D; ++dd) {
            float s = 0.f;
#pragma unroll
            for (int r = 0; r < SL; ++r) s += gldf(&g_sums[r * (B * KC * D) + t * D + dd]);
            float c = s / cnt;
            s_cF[t * 17 + dd] = c;
            ns += c * c;
        }
        acc = sqrtf(ns) / (float)KC;
    }
    if (t < 64) acc += gldf(&g_varp[t]);
    __syncthreads();

    float dacc = 0.f;  // raw sum over [B,K,K] incl. diagonal (= delta_dist^2 each)
    for (int idx = t; idx < B * KC * KC; idx += TPB) {
        int bb = idx / (KC * KC);
        int r = idx % (KC * KC);
        int i = r / KC, j = r % KC;
        float hd;
        if (i == j) {
            hd = DELTA_DIST * DELTA_DIST;
        } else {
            const float* ci = &s_cF[(bb * KC + i) * 17];
            const float* cj = &s_cF[(bb * KC + j) * 17];
            float sq = 0.f;
            for (int dd = 0; dd < D; ++dd) { float df = ci[dd] - cj[dd]; sq += df * df; }
            float hh = fmaxf(DELTA_DIST - sqrtf(sq), 0.f);
            hd = hh * hh;
        }
        dacc += hd;
    }
    float total = acc + dacc / (2.f * KC * (KC - 1));

    for (int o = 32; o > 0; o >>= 1) total += __shfl_down(total, o, 64);
    if ((t & 63) == 0) s_red[t >> 6] = total;
    __syncthreads();
    if (t == 0) {
        float s = 0.f;
#pragma unroll
        for (int w = 0; w < 8; ++w) s += s_red[w];
        out[0] = s / (float)B;
    }
}

extern "C" void kernel_launch(void* const* d_in, const int* in_sizes, int n_in,
                              void* d_out, int out_size, void* d_ws, size_t ws_size,
                              hipStream_t stream) {
    const float* data  = (const float*)d_in[0];
    const int* labels  = (const int*)d_in[1];
    float* ws          = (float*)d_ws;

    hipMemsetAsync(d_ws, 0, WS_FLOATS * sizeof(float) + 2 * sizeof(int), stream);
    k_fused<<<NBLK, TPB, 0, stream>>>(data, labels, ws, (float*)d_out);
}

// Round 6
// 387.565 us; speedup vs baseline: 1.0284x; 1.0284x over previous
//
#include <hip/hip_runtime.h>
#include <math.h>

#define KC 24
constexpr int D = 16;
constexpr int B = 4;
constexpr int N = 512 * 1024;          // points per image, 2^19
constexpr float DELTA_VAR = 1.0f;
constexpr float DELTA_DIST = 2.0f;

constexpr int REP = 8;                 // LDS accumulator replicas (replica = t&7)
constexpr int RS  = KC * 17;           // 408 words per sum replica
constexpr int CS  = 33;
constexpr int TPB = 512;
constexpr int PTS = 8192;              // points per block (16 per thread)
constexpr int NBLK = (B * N) / PTS;    // 256 blocks; 147KB LDS forces 1 block/CU -> all resident
constexpr int SL = 8;                  // global accumulator slices
constexpr int WS_FLOATS = SL * (B * KC * D) + SL * (B * KC) + 64;  // 13120

// ws: g_sums [SL][B*KC*D] | g_cnt [SL][B*KC] | g_varp [64] | barrier {cnt,gen}

__device__ __forceinline__ float gldf(const float* p) {
    return __hip_atomic_load(p, __ATOMIC_RELAXED, __HIP_MEMORY_SCOPE_AGENT);
}

// sense-reversing grid barrier; bounded spin so a residency failure fails visibly, not hangs
__device__ __forceinline__ void gsync(int* cnt, int* gen) {
    __syncthreads();
    if (threadIdx.x == 0) {
        int g = __hip_atomic_load(gen, __ATOMIC_ACQUIRE, __HIP_MEMORY_SCOPE_AGENT);
        if (__hip_atomic_fetch_add(cnt, 1, __ATOMIC_ACQ_REL, __HIP_MEMORY_SCOPE_AGENT) == NBLK - 1) {
            __hip_atomic_store(cnt, 0, __ATOMIC_RELAXED, __HIP_MEMORY_SCOPE_AGENT);
            __hip_atomic_fetch_add(gen, 1, __ATOMIC_ACQ_REL, __HIP_MEMORY_SCOPE_AGENT);
        } else {
            for (int it = 0; it < (1 << 24); ++it) {
                if (__hip_atomic_load(gen, __ATOMIC_ACQUIRE, __HIP_MEMORY_SCOPE_AGENT) != g) break;
                __builtin_amdgcn_s_sleep(2);
            }
        }
    }
    __syncthreads();
}

// bf16x2 unpack (truncation packing: lo point in bits[15:0], hi point in bits[31:16])
__device__ __forceinline__ float blo(unsigned u) { return __uint_as_float(u << 16); }
__device__ __forceinline__ float bhi(unsigned u) { return __uint_as_float(u & 0xFFFF0000u); }

__global__ __launch_bounds__(TPB, 2) void k_fused(const float* __restrict__ data,
                                                  const int* __restrict__ labels,
                                                  float* __restrict__ ws,
                                                  float* __restrict__ out) {
    __shared__ float s_sum[REP * RS];          // 13056 B
    __shared__ float s_cnt[REP * CS];          // 1056 B
    __shared__ uint2 s_xb[8][PTS / 4];         // planes 0..7 bf16x2-packed: 131072 B
    __shared__ float s_c[KC * 17];             // 1632 B
    __shared__ float s_ic[KC];
    __shared__ float s_c2[KC];
    __shared__ float s_red[8];

    float* g_sums = ws;
    float* g_cnt  = ws + SL * (B * KC * D);
    float* g_varp = g_cnt + SL * (B * KC);
    int*   bar    = (int*)(g_varp + 64);

    const int t = threadIdx.x;
    const int chunk = blockIdx.x * PTS;
    const int b = chunk >> 19;
    const float* base = data + (size_t)(b * D) * N + (chunk & (N - 1));

    // early global loads (labels + plane 0) overlap the LDS zeroing
    int4 lab[4];
#pragma unroll
    for (int i = 0; i < 4; ++i)
        lab[i] = *(const int4*)(labels + chunk + (i * TPB + t) * 4);

    float4 va[4], vb[4];
#pragma unroll
    for (int i = 0; i < 4; ++i)
        va[i] = *(const float4*)(base + (i * TPB + t) * 4);

    for (int i = t; i < REP * RS; i += TPB) s_sum[i] = 0.f;
    for (int i = t; i < REP * CS; i += TPB) s_cnt[i] = 0.f;
    __syncthreads();

    const int rbase = (t & 7) * RS;
    const int cbase = (t & 7) * CS;
#pragma unroll
    for (int i = 0; i < 4; ++i) {
        atomicAdd(&s_cnt[cbase + lab[i].x], 1.f);
        atomicAdd(&s_cnt[cbase + lab[i].y], 1.f);
        atomicAdd(&s_cnt[cbase + lab[i].z], 1.f);
        atomicAdd(&s_cnt[cbase + lab[i].w], 1.f);
    }

    // ---- phase 1: d-sequential accumulate; retain ||x||^2 (f32) + x (bf16) ----
    float r2[16];
#pragma unroll
    for (int p = 0; p < 16; ++p) r2[p] = 0.f;
    unsigned xb[8][8];                 // planes 8..15, [plane][i*2 + pair]

#pragma unroll
    for (int d = 0; d < D; ++d) {
        if (d + 1 < D) {
#pragma unroll
            for (int i = 0; i < 4; ++i) {
                float4 nx = *(const float4*)(base + (size_t)(d + 1) * N + (i * TPB + t) * 4);
                if ((d + 1) & 1) vb[i] = nx; else va[i] = nx;
            }
        }
#pragma unroll
        for (int i = 0; i < 4; ++i) {
            const float4 c = (d & 1) ? vb[i] : va[i];
            r2[i * 4 + 0] = fmaf(c.x, c.x, r2[i * 4 + 0]);
            r2[i * 4 + 1] = fmaf(c.y, c.y, r2[i * 4 + 1]);
            r2[i * 4 + 2] = fmaf(c.z, c.z, r2[i * 4 + 2]);
            r2[i * 4 + 3] = fmaf(c.w, c.w, r2[i * 4 + 3]);
            unsigned pxy = (__float_as_uint(c.y) & 0xFFFF0000u) | (__float_as_uint(c.x) >> 16);
            unsigned pzw = (__float_as_uint(c.w) & 0xFFFF0000u) | (__float_as_uint(c.z) >> 16);
            if (d < 8) s_xb[d][i * TPB + t] = make_uint2(pxy, pzw);
            else       { xb[d - 8][i * 2 + 0] = pxy; xb[d - 8][i * 2 + 1] = pzw; }
            atomicAdd(&s_sum[rbase + lab[i].x * 17 + d], c.x);
            atomicAdd(&s_sum[rbase + lab[i].y * 17 + d], c.y);
            atomicAdd(&s_sum[rbase + lab[i].z * 17 + d], c.z);
            atomicAdd(&s_sum[rbase + lab[i].w * 17 + d], c.w);
        }
    }

    // pin retained state: opaque asm outputs cannot be rematerialized from global
#pragma unroll
    for (int dd = 0; dd < 8; ++dd)
#pragma unroll
        for (int q = 0; q < 8; ++q) asm volatile("" : "+v"(xb[dd][q]));
#pragma unroll
    for (int p = 0; p < 16; ++p) asm volatile("" : "+v"(r2[p]));
#pragma unroll
    for (int i = 0; i < 4; ++i)
        asm volatile("" : "+v"(lab[i].x), "+v"(lab[i].y), "+v"(lab[i].z), "+v"(lab[i].w));

    __syncthreads();

    // epilogue: rotated order + per-slice targets
    const int slice = blockIdx.x & (SL - 1);
    float* gs = g_sums + slice * (B * KC * D) + b * (KC * D);
    float* gc = g_cnt  + slice * (B * KC)     + b * KC;
    const int rot = (blockIdx.x * 131) & 255;
    for (int i = t; i < KC * D; i += TPB) {
        int j = (i + rot) % (KC * D);
        int c = j >> 4, dd = j & 15;
        float s = 0.f;
#pragma unroll
        for (int r = 0; r < REP; ++r) s += s_sum[r * RS + c * 17 + dd];
        atomicAdd(&gs[j], s);
    }
    if (t < KC) {
        float s = 0.f;
#pragma unroll
        for (int r = 0; r < REP; ++r) s += s_cnt[r * CS + t];
        atomicAdd(&gc[t], s);
    }

    gsync(bar, bar + 1);   // sums + counts final

    // ---- phase 2: centers + hinged variance (ZERO global data loads) ----
    if (t < KC) {
        float cn = 0.f;
#pragma unroll
        for (int r = 0; r < SL; ++r) cn += gldf(&g_cnt[r * (B * KC) + b * KC + t]);
        s_ic[t] = 1.f / cn;
    }
    __syncthreads();
    for (int i = t; i < KC * D; i += TPB) {
        int c = i >> 4, dd = i & 15;
        float s = 0.f;
#pragma unroll
        for (int r = 0; r < SL; ++r) s += gldf(&g_sums[r * (B * KC * D) + b * (KC * D) + i]);
        s_c[c * 17 + dd] = s * s_ic[c];
    }
    __syncthreads();
    if (t < KC) {
        float q = 0.f;
#pragma unroll
        for (int dd = 0; dd < D; ++dd) q = fmaf(s_c[t * 17 + dd], s_c[t * 17 + dd], q);
        s_c2[t] = q;
    }
    __syncthreads();

    float hsum = 0.f;
#pragma unroll
    for (int i = 0; i < 4; ++i) {
        const float* cx = &s_c[lab[i].x * 17];
        const float* cy = &s_c[lab[i].y * 17];
        const float* cz = &s_c[lab[i].z * 17];
        const float* cw = &s_c[lab[i].w * 17];
        float d0 = 0.f, d1 = 0.f, d2 = 0.f, d3 = 0.f;
#pragma unroll
        for (int d = 0; d < 8; ++d) {          // LDS planes 0..7
            uint2 u = s_xb[d][i * TPB + t];
            d0 = fmaf(blo(u.x), cx[d], d0);
            d1 = fmaf(bhi(u.x), cy[d], d1);
            d2 = fmaf(blo(u.y), cz[d], d2);
            d3 = fmaf(bhi(u.y), cw[d], d3);
        }
#pragma unroll
        for (int d = 0; d < 8; ++d) {          // register planes 8..15
            d0 = fmaf(blo(xb[d][i * 2 + 0]), cx[8 + d], d0);
            d1 = fmaf(bhi(xb[d][i * 2 + 0]), cy[8 + d], d1);
            d2 = fmaf(blo(xb[d][i * 2 + 1]), cz[8 + d], d2);
            d3 = fmaf(bhi(xb[d][i * 2 + 1]), cw[8 + d], d3);
        }
        float q, h;
        q = fmaxf(fmaf(-2.f, d0, r2[i * 4 + 0]) + s_c2[lab[i].x], 0.f);
        h = fmaxf(sqrtf(q) - DELTA_VAR, 0.f); hsum += h * h * s_ic[lab[i].x];
        q = fmaxf(fmaf(-2.f, d1, r2[i * 4 + 1]) + s_c2[lab[i].y], 0.f);
        h = fmaxf(sqrtf(q) - DELTA_VAR, 0.f); hsum += h * h * s_ic[lab[i].y];
        q = fmaxf(fmaf(-2.f, d2, r2[i * 4 + 2]) + s_c2[lab[i].z], 0.f);
        h = fmaxf(sqrtf(q) - DELTA_VAR, 0.f); hsum += h * h * s_ic[lab[i].z];
        q = fmaxf(fmaf(-2.f, d3, r2[i * 4 + 3]) + s_c2[lab[i].w], 0.f);
        h = fmaxf(sqrtf(q) - DELTA_VAR, 0.f); hsum += h * h * s_ic[lab[i].w];
    }
    for (int o = 32; o > 0; o >>= 1) hsum += __shfl_down(hsum, o, 64);
    if ((t & 63) == 0) s_red[t >> 6] = hsum;
    __syncthreads();
    if (t == 0) {
        float s = 0.f;
#pragma unroll
        for (int w = 0; w < 8; ++w) s += s_red[w];
        atomicAdd(&g_varp[blockIdx.x & 63], s);
    }

    gsync(bar, bar + 1);   // varp final

    if (blockIdx.x != 0) return;

    // ---- finalize (block 0): var + dist + reg -> scalar ----
    float* s_cF = (float*)&s_xb[0][0];   // reuse 128 KB region; needs 6528 floats
    float acc = 0.f;
    if (t < B * KC) {
        float cnt = 0.f;
#pragma unroll
        for (int r = 0; r < SL; ++r) cnt += gldf(&g_cnt[r * (B * KC) + t]);
        float ns = 0.f;
        for (int dd = 0; dd < D; ++dd) {
            float s = 0.f;
#pragma unroll
            for (int r = 0; r < SL; ++r) s += gldf(&g_sums[r * (B * KC * D) + t * D + dd]);
            float c = s / cnt;
            s_cF[t * 17 + dd] = c;
            ns += c * c;
        }
        acc = sqrtf(ns) / (float)KC;
    }
    if (t < 64) acc += gldf(&g_varp[t]);
    __syncthreads();

    float dacc = 0.f;  // raw sum over [B,K,K] incl. diagonal (= delta_dist^2 each)
    for (int idx = t; idx < B * KC * KC; idx += TPB) {
        int bb = idx / (KC * KC);
        int r = idx % (KC * KC);
        int i = r / KC, j = r % KC;
        float hd;
        if (i == j) {
            hd = DELTA_DIST * DELTA_DIST;
        } else {
            const float* ci = &s_cF[(bb * KC + i) * 17];
            const float* cj = &s_cF[(bb * KC + j) * 17];
            float sq = 0.f;
            for (int dd = 0; dd < D; ++dd) { float df = ci[dd] - cj[dd]; sq += df * df; }
            float hh = fmaxf(DELTA_DIST - sqrtf(sq), 0.f);
            hd = hh * hh;
        }
        dacc += hd;
    }
    float total = acc + dacc / (2.f * KC * (KC - 1));

    for (int o = 32; o > 0; o >>= 1) total += __shfl_down(total, o, 64);
    if ((t & 63) == 0) s_red[t >> 6] = total;
    __syncthreads();
    if (t == 0) {
        float s = 0.f;
#pragma unroll
        for (int w = 0; w < 8; ++w) s += s_red[w];
        out[0] = s / (float)B;
    }
}

extern "C" void kernel_launch(void* const* d_in, const int* in_sizes, int n_in,
                              void* d_out, int out_size, void* d_ws, size_t ws_size,
                              hipStream_t stream) {
    const float* data  = (const float*)d_in[0];
    const int* labels  = (const int*)d_in[1];
    float* ws          = (float*)d_ws;

    hipMemsetAsync(d_ws, 0, WS_FLOATS * sizeof(float) + 2 * sizeof(int), stream);
    k_fused<<<NBLK, TPB, 0, stream>>>(data, labels, ws, (float*)d_out);
}

// Round 7
// 364.700 us; speedup vs baseline: 1.0929x; 1.0627x over previous
//
#include <hip/hip_runtime.h>
#include <math.h>

#define KC 24
constexpr int D = 16;
constexpr int B = 4;
constexpr int N = 512 * 1024;          // points per image, 2^19
constexpr float DELTA_VAR = 1.0f;
constexpr float DELTA_DIST = 2.0f;

constexpr int REP = 8;                 // LDS accumulator replicas (replica = t&7)
constexpr int RS  = KC * 17;           // 408 words per sum replica
constexpr int CS  = 33;
constexpr int TPB = 512;
constexpr int PTS = 8192;              // points per block (16 per thread)
constexpr int NBLK = (B * N) / PTS;    // 256 blocks; 147KB LDS forces 1 block/CU -> all resident
constexpr int SL = 8;                  // global accumulator slices
constexpr int WS_FLOATS = SL * (B * KC * D) + SL * (B * KC) + 64;  // 13120

// ws: g_sums [SL][B*KC*D] | g_cnt [SL][B*KC] | g_varp [64] | barrier {cnt,gen}

__device__ __forceinline__ float gldf(const float* p) {
    return __hip_atomic_load(p, __ATOMIC_RELAXED, __HIP_MEMORY_SCOPE_AGENT);
}

// sense-reversing grid barrier; bounded spin so a residency failure fails visibly, not hangs
__device__ __forceinline__ void gsync(int* cnt, int* gen) {
    __syncthreads();
    if (threadIdx.x == 0) {
        int g = __hip_atomic_load(gen, __ATOMIC_ACQUIRE, __HIP_MEMORY_SCOPE_AGENT);
        if (__hip_atomic_fetch_add(cnt, 1, __ATOMIC_ACQ_REL, __HIP_MEMORY_SCOPE_AGENT) == NBLK - 1) {
            __hip_atomic_store(cnt, 0, __ATOMIC_RELAXED, __HIP_MEMORY_SCOPE_AGENT);
            __hip_atomic_fetch_add(gen, 1, __ATOMIC_ACQ_REL, __HIP_MEMORY_SCOPE_AGENT);
        } else {
            for (int it = 0; it < (1 << 22); ++it) {
                if (__hip_atomic_load(gen, __ATOMIC_ACQUIRE, __HIP_MEMORY_SCOPE_AGENT) != g) break;
                __builtin_amdgcn_s_sleep(32);   // ~2K-cycle poll: low contention on release line
            }
        }
    }
    __syncthreads();
}

// bf16x2 unpack (truncation packing: lo point in bits[15:0], hi point in bits[31:16])
__device__ __forceinline__ float blo(unsigned u) { return __uint_as_float(u << 16); }
__device__ __forceinline__ float bhi(unsigned u) { return __uint_as_float(u & 0xFFFF0000u); }

__global__ __launch_bounds__(TPB) void k_fused(const float* __restrict__ data,
                                               const int* __restrict__ labels,
                                               float* __restrict__ ws) {
    __shared__ float s_sum[REP * RS];          // 13056 B
    __shared__ float s_cnt[REP * CS];          // 1056 B
    __shared__ uint2 s_xb[8][PTS / 4];         // planes 0..7 bf16x2-packed: 131072 B
    __shared__ float s_c[KC * 17];             // 1632 B
    __shared__ float s_ic[KC];
    __shared__ float s_c2[KC];
    __shared__ float s_red[8];

    float* g_sums = ws;
    float* g_cnt  = ws + SL * (B * KC * D);
    float* g_varp = g_cnt + SL * (B * KC);
    int*   bar    = (int*)(g_varp + 64);

    const int t = threadIdx.x;
    const int chunk = blockIdx.x * PTS;
    const int b = chunk >> 19;
    const float* base = data + (size_t)(b * D) * N + (chunk & (N - 1));

    // early global loads (labels + plane 0) overlap the LDS zeroing
    int4 lab[4];
#pragma unroll
    for (int i = 0; i < 4; ++i)
        lab[i] = *(const int4*)(labels + chunk + (i * TPB + t) * 4);

    float4 va[4], vb[4];
#pragma unroll
    for (int i = 0; i < 4; ++i)
        va[i] = *(const float4*)(base + (i * TPB + t) * 4);

    for (int i = t; i < REP * RS; i += TPB) s_sum[i] = 0.f;
    for (int i = t; i < REP * CS; i += TPB) s_cnt[i] = 0.f;
    __syncthreads();

    const int rbase = (t & 7) * RS;
    const int cbase = (t & 7) * CS;
#pragma unroll
    for (int i = 0; i < 4; ++i) {
        atomicAdd(&s_cnt[cbase + lab[i].x], 1.f);
        atomicAdd(&s_cnt[cbase + lab[i].y], 1.f);
        atomicAdd(&s_cnt[cbase + lab[i].z], 1.f);
        atomicAdd(&s_cnt[cbase + lab[i].w], 1.f);
    }

    // ---- phase 1: d-sequential accumulate; retain ||x||^2 (f32) + x (bf16) ----
    float r2[16];
#pragma unroll
    for (int p = 0; p < 16; ++p) r2[p] = 0.f;
    unsigned xb[8][8];                 // planes 8..15, [plane][i*2 + pair]

#pragma unroll
    for (int d = 0; d < D; ++d) {
        if (d + 1 < D) {
#pragma unroll
            for (int i = 0; i < 4; ++i) {
                float4 nx = *(const float4*)(base + (size_t)(d + 1) * N + (i * TPB + t) * 4);
                if ((d + 1) & 1) vb[i] = nx; else va[i] = nx;
            }
        }
#pragma unroll
        for (int i = 0; i < 4; ++i) {
            const float4 c = (d & 1) ? vb[i] : va[i];
            r2[i * 4 + 0] = fmaf(c.x, c.x, r2[i * 4 + 0]);
            r2[i * 4 + 1] = fmaf(c.y, c.y, r2[i * 4 + 1]);
            r2[i * 4 + 2] = fmaf(c.z, c.z, r2[i * 4 + 2]);
            r2[i * 4 + 3] = fmaf(c.w, c.w, r2[i * 4 + 3]);
            unsigned pxy = (__float_as_uint(c.y) & 0xFFFF0000u) | (__float_as_uint(c.x) >> 16);
            unsigned pzw = (__float_as_uint(c.w) & 0xFFFF0000u) | (__float_as_uint(c.z) >> 16);
            if (d < 8) s_xb[d][i * TPB + t] = make_uint2(pxy, pzw);
            else       { xb[d - 8][i * 2 + 0] = pxy; xb[d - 8][i * 2 + 1] = pzw; }
            atomicAdd(&s_sum[rbase + lab[i].x * 17 + d], c.x);
            atomicAdd(&s_sum[rbase + lab[i].y * 17 + d], c.y);
            atomicAdd(&s_sum[rbase + lab[i].z * 17 + d], c.z);
            atomicAdd(&s_sum[rbase + lab[i].w * 17 + d], c.w);
        }
    }

    // pin retained state: opaque asm outputs cannot be rematerialized from global
#pragma unroll
    for (int dd = 0; dd < 8; ++dd)
#pragma unroll
        for (int q = 0; q < 8; ++q) asm volatile("" : "+v"(xb[dd][q]));
#pragma unroll
    for (int p = 0; p < 16; ++p) asm volatile("" : "+v"(r2[p]));
#pragma unroll
    for (int i = 0; i < 4; ++i)
        asm volatile("" : "+v"(lab[i].x), "+v"(lab[i].y), "+v"(lab[i].z), "+v"(lab[i].w));

    __syncthreads();

    // epilogue: rotated order + per-slice targets
    const int slice = blockIdx.x & (SL - 1);
    float* gs = g_sums + slice * (B * KC * D) + b * (KC * D);
    float* gc = g_cnt  + slice * (B * KC)     + b * KC;
    const int rot = (blockIdx.x * 131) & 255;
    for (int i = t; i < KC * D; i += TPB) {
        int j = (i + rot) % (KC * D);
        int c = j >> 4, dd = j & 15;
        float s = 0.f;
#pragma unroll
        for (int r = 0; r < REP; ++r) s += s_sum[r * RS + c * 17 + dd];
        atomicAdd(&gs[j], s);
    }
    if (t < KC) {
        float s = 0.f;
#pragma unroll
        for (int r = 0; r < REP; ++r) s += s_cnt[r * CS + t];
        atomicAdd(&gc[t], s);
    }

    gsync(bar, bar + 1);   // THE single grid barrier: sums + counts final

    // ---- phase 2: centers + hinged variance (ZERO global data loads) ----
    if (t < KC) {
        float cn = 0.f;
#pragma unroll
        for (int r = 0; r < SL; ++r) cn += gldf(&g_cnt[r * (B * KC) + b * KC + t]);
        s_ic[t] = 1.f / cn;
    }
    __syncthreads();
    for (int i = t; i < KC * D; i += TPB) {
        int c = i >> 4, dd = i & 15;
        float s = 0.f;
#pragma unroll
        for (int r = 0; r < SL; ++r) s += gldf(&g_sums[r * (B * KC * D) + b * (KC * D) + i]);
        s_c[c * 17 + dd] = s * s_ic[c];
    }
    __syncthreads();
    if (t < KC) {
        float q = 0.f;
#pragma unroll
        for (int dd = 0; dd < D; ++dd) q = fmaf(s_c[t * 17 + dd], s_c[t * 17 + dd], q);
        s_c2[t] = q;
    }
    __syncthreads();

    float hsum = 0.f;
#pragma unroll
    for (int i = 0; i < 4; ++i) {
        const float* cx = &s_c[lab[i].x * 17];
        const float* cy = &s_c[lab[i].y * 17];
        const float* cz = &s_c[lab[i].z * 17];
        const float* cw = &s_c[lab[i].w * 17];
        float d0 = 0.f, d1 = 0.f, d2 = 0.f, d3 = 0.f;
#pragma unroll
        for (int d = 0; d < 8; ++d) {          // LDS planes 0..7
            uint2 u = s_xb[d][i * TPB + t];
            d0 = fmaf(blo(u.x), cx[d], d0);
            d1 = fmaf(bhi(u.x), cy[d], d1);
            d2 = fmaf(blo(u.y), cz[d], d2);
            d3 = fmaf(bhi(u.y), cw[d], d3);
        }
#pragma unroll
        for (int d = 0; d < 8; ++d) {          // register planes 8..15
            d0 = fmaf(blo(xb[d][i * 2 + 0]), cx[8 + d], d0);
            d1 = fmaf(bhi(xb[d][i * 2 + 0]), cy[8 + d], d1);
            d2 = fmaf(blo(xb[d][i * 2 + 1]), cz[8 + d], d2);
            d3 = fmaf(bhi(xb[d][i * 2 + 1]), cw[8 + d], d3);
        }
        float q, h;
        q = fmaxf(fmaf(-2.f, d0, r2[i * 4 + 0]) + s_c2[lab[i].x], 0.f);
        h = fmaxf(sqrtf(q) - DELTA_VAR, 0.f); hsum += h * h * s_ic[lab[i].x];
        q = fmaxf(fmaf(-2.f, d1, r2[i * 4 + 1]) + s_c2[lab[i].y], 0.f);
        h = fmaxf(sqrtf(q) - DELTA_VAR, 0.f); hsum += h * h * s_ic[lab[i].y];
        q = fmaxf(fmaf(-2.f, d2, r2[i * 4 + 2]) + s_c2[lab[i].z], 0.f);
        h = fmaxf(sqrtf(q) - DELTA_VAR, 0.f); hsum += h * h * s_ic[lab[i].z];
        q = fmaxf(fmaf(-2.f, d3, r2[i * 4 + 3]) + s_c2[lab[i].w], 0.f);
        h = fmaxf(sqrtf(q) - DELTA_VAR, 0.f); hsum += h * h * s_ic[lab[i].w];
    }
    for (int o = 32; o > 0; o >>= 1) hsum += __shfl_down(hsum, o, 64);
    if ((t & 63) == 0) s_red[t >> 6] = hsum;
    __syncthreads();
    if (t == 0) {
        float s = 0.f;
#pragma unroll
        for (int w = 0; w < 8; ++w) s += s_red[w];
        atomicAdd(&g_varp[blockIdx.x & 63], s);
    }
    // no second barrier: kernel boundary syncs before k_final
}

// ---------------- Finalize: var + dist + reg -> scalar (separate tiny launch) ----------------
__global__ __launch_bounds__(128) void k_final(const float* __restrict__ ws,
                                               float* __restrict__ out) {
    const float* g_sums = ws;
    const float* g_cnt  = ws + SL * (B * KC * D);
    const float* g_varp = g_cnt + SL * (B * KC);

    __shared__ float s_c[B * KC * 17];
    __shared__ float s_red[2];
    const int t = threadIdx.x;

    float acc = 0.f;
    if (t < B * KC) {               // reg term + center build (sum the SL slices)
        float cnt = 0.f;
#pragma unroll
        for (int r = 0; r < SL; ++r) cnt += g_cnt[r * (B * KC) + t];
        float ns = 0.f;
        for (int dd = 0; dd < D; ++dd) {
            float s = 0.f;
#pragma unroll
            for (int r = 0; r < SL; ++r) s += g_sums[r * (B * KC * D) + t * D + dd];
            float c = s / cnt;
            s_c[t * 17 + dd] = c;
            ns += c * c;
        }
        acc = sqrtf(ns) / (float)KC;
    }
    if (t < 64) acc += g_varp[t];   // var term partials
    __syncthreads();

    float dacc = 0.f;  // raw sum over [B,K,K] incl. diagonal (= delta_dist^2 each)
    for (int idx = t; idx < B * KC * KC; idx += 128) {
        int b = idx / (KC * KC);
        int r = idx % (KC * KC);
        int i = r / KC, j = r % KC;
        float hd;
        if (i == j) {
            hd = DELTA_DIST * DELTA_DIST;
        } else {
            const float* ci = &s_c[(b * KC + i) * 17];
            const float* cj = &s_c[(b * KC + j) * 17];
            float sq = 0.f;
            for (int dd = 0; dd < D; ++dd) { float df = ci[dd] - cj[dd]; sq += df * df; }
            float hh = fmaxf(DELTA_DIST - sqrtf(sq), 0.f);
            hd = hh * hh;
        }
        dacc += hd;
    }
    float total = acc + dacc / (2.f * KC * (KC - 1));

    for (int o = 32; o > 0; o >>= 1) total += __shfl_down(total, o, 64);
    if ((t & 63) == 0) s_red[t >> 6] = total;
    __syncthreads();
    if (t == 0) out[0] = (s_red[0] + s_red[1]) / (float)B;
}

extern "C" void kernel_launch(void* const* d_in, const int* in_sizes, int n_in,
                              void* d_out, int out_size, void* d_ws, size_t ws_size,
                              hipStream_t stream) {
    const float* data  = (const float*)d_in[0];
    const int* labels  = (const int*)d_in[1];
    float* ws          = (float*)d_ws;

    hipMemsetAsync(d_ws, 0, WS_FLOATS * sizeof(float) + 2 * sizeof(int), stream);
    k_fused<<<NBLK, TPB, 0, stream>>>(data, labels, ws);
    k_final<<<1, 128, 0, stream>>>(ws, (float*)d_out);
}

// Round 8
// 347.090 us; speedup vs baseline: 1.1484x; 1.0507x over previous
//
#include <hip/hip_runtime.h>
#include <math.h>

#define KC 24
constexpr int D = 16;
constexpr int B = 4;
constexpr int N = 512 * 1024;          // points per image, 2^19
constexpr float DELTA_VAR = 1.0f;
constexpr float DELTA_DIST = 2.0f;

constexpr int REP = 8;                 // LDS accumulator replicas (replica = lane&7)
constexpr int RS  = KC * 17;           // 408 words per sum replica
constexpr int CS  = 33;
constexpr int PTS = 4096;              // points per block, 16/thread
constexpr int TPB = 256;
constexpr int NBLK = (B * N) / PTS;    // 512
constexpr int SL = 8;                  // global accumulator slices
constexpr int SMALL = SL * (B * KC * D) + SL * (B * KC) + 64;   // 13120 floats
// handoff: r2g [B*N] f32 (8 MB) | xbg [D][B*N/2] bf16x2 (64 MB)
constexpr size_t NEED = ((size_t)SMALL + (size_t)B * N) * 4 + (size_t)D * (B * N / 2) * 4;

// bf16x2 unpack (truncation packing: even point in bits[15:0], odd in bits[31:16])
__device__ __forceinline__ float blo(unsigned u) { return __uint_as_float(u << 16); }
__device__ __forceinline__ float bhi(unsigned u) { return __uint_as_float(u & 0xFFFF0000u); }

// ---------------- shared phase-1 body; HANDOFF=1 also writes bf16 x + f32 ||x||^2 ----------------
template <int HANDOFF>
__device__ __forceinline__ void p1_body(const float* __restrict__ data,
                                        const int* __restrict__ labels,
                                        float* __restrict__ ws) {
    __shared__ float s_sum[REP * RS];
    __shared__ float s_cnt[REP * CS];
    float* g_sums = ws;
    float* g_cnt  = ws + SL * (B * KC * D);
    float* r2g    = ws + SMALL;
    unsigned* xbg = (unsigned*)(ws + SMALL + B * N);

    const int t = threadIdx.x;
    const int chunk = blockIdx.x * PTS;
    const int b     = chunk >> 19;
    const int n0    = chunk & (N - 1);

    int4 lab[4];
#pragma unroll
    for (int i = 0; i < 4; ++i)
        lab[i] = *(const int4*)(labels + chunk + (i * TPB + t) * 4);

    const float* base = data + (size_t)(b * D) * N + n0;
    float4 v[2][4];
#pragma unroll
    for (int i = 0; i < 4; ++i)
        v[0][i] = *(const float4*)(base + (i * TPB + t) * 4);

    for (int i = t; i < REP * RS; i += TPB) s_sum[i] = 0.f;
    for (int i = t; i < REP * CS; i += TPB) s_cnt[i] = 0.f;

    const int rbase = (t & 7) * RS;
    int adr[4][4];
#pragma unroll
    for (int i = 0; i < 4; ++i) {
        adr[i][0] = rbase + lab[i].x * 17;
        adr[i][1] = rbase + lab[i].y * 17;
        adr[i][2] = rbase + lab[i].z * 17;
        adr[i][3] = rbase + lab[i].w * 17;
    }
    __syncthreads();

    const int cbase = (t & 7) * CS;
#pragma unroll
    for (int i = 0; i < 4; ++i) {
        atomicAdd(&s_cnt[cbase + lab[i].x], 1.f);
        atomicAdd(&s_cnt[cbase + lab[i].y], 1.f);
        atomicAdd(&s_cnt[cbase + lab[i].z], 1.f);
        atomicAdd(&s_cnt[cbase + lab[i].w], 1.f);
    }

    float4 r2v[4];
#pragma unroll
    for (int i = 0; i < 4; ++i) r2v[i] = make_float4(0.f, 0.f, 0.f, 0.f);

#pragma unroll
    for (int d = 0; d < D; ++d) {
        if (d + 1 < D) {
#pragma unroll
            for (int i = 0; i < 4; ++i)
                v[(d + 1) & 1][i] =
                    *(const float4*)(base + (size_t)(d + 1) * N + (i * TPB + t) * 4);
        }
        unsigned* xrow = xbg + (size_t)d * (B * N / 2) + (chunk >> 1);
#pragma unroll
        for (int i = 0; i < 4; ++i) {
            const float4 c = v[d & 1][i];
            if (HANDOFF) {
                r2v[i].x = fmaf(c.x, c.x, r2v[i].x);
                r2v[i].y = fmaf(c.y, c.y, r2v[i].y);
                r2v[i].z = fmaf(c.z, c.z, r2v[i].z);
                r2v[i].w = fmaf(c.w, c.w, r2v[i].w);
                uint2 pk;
                pk.x = (__float_as_uint(c.y) & 0xFFFF0000u) | (__float_as_uint(c.x) >> 16);
                pk.y = (__float_as_uint(c.w) & 0xFFFF0000u) | (__float_as_uint(c.z) >> 16);
                *(uint2*)(xrow + (i * TPB + t) * 2) = pk;
            }
            atomicAdd(&s_sum[adr[i][0] + d], c.x);
            atomicAdd(&s_sum[adr[i][1] + d], c.y);
            atomicAdd(&s_sum[adr[i][2] + d], c.z);
            atomicAdd(&s_sum[adr[i][3] + d], c.w);
        }
    }
    if (HANDOFF) {
#pragma unroll
        for (int i = 0; i < 4; ++i)
            *(float4*)(r2g + chunk + (i * TPB + t) * 4) = r2v[i];
    }
    __syncthreads();

    const int slice = blockIdx.x & (SL - 1);
    float* gs = g_sums + slice * (B * KC * D) + b * (KC * D);
    float* gc = g_cnt  + slice * (B * KC)     + b * KC;
    const int rot = (blockIdx.x * 131) & 255;
    for (int i = t; i < KC * D; i += TPB) {
        int j = (i + rot) % (KC * D);
        int c = j >> 4, dd = j & 15;
        float s = 0.f;
#pragma unroll
        for (int r = 0; r < REP; ++r) s += s_sum[r * RS + c * 17 + dd];
        atomicAdd(&gs[j], s);
    }
    if (t < KC) {
        float s = 0.f;
#pragma unroll
        for (int r = 0; r < REP; ++r) s += s_cnt[r * CS + t];
        atomicAdd(&gc[t], s);
    }
}

__global__ __launch_bounds__(TPB) void k_p1(const float* __restrict__ data,
                                            const int* __restrict__ labels,
                                            float* __restrict__ ws) {
    p1_body<1>(data, labels, ws);
}

__global__ __launch_bounds__(TPB) void k_sums(const float* __restrict__ data,
                                              const int* __restrict__ labels,
                                              float* __restrict__ ws) {
    p1_body<0>(data, labels, ws);
}

// ---------------- P2: hinged variance from compressed handoff (80 MB) ----------------
__global__ __launch_bounds__(TPB) void k_p2(const int* __restrict__ labels,
                                            float* __restrict__ ws) {
    __shared__ float s_c[KC * 17];
    __shared__ float s_ic[KC];
    __shared__ float s_c2[KC];
    __shared__ float s_part[4];
    float* g_sums = ws;
    float* g_cnt  = ws + SL * (B * KC * D);
    float* g_varp = g_cnt + SL * (B * KC);
    const float* r2g    = ws + SMALL;
    const unsigned* xbg = (const unsigned*)(ws + SMALL + B * N);

    const int t = threadIdx.x;
    const int chunk = blockIdx.x * PTS;
    const int b     = chunk >> 19;

    // early per-thread loads overlap the center build
    int4 lab[4];
#pragma unroll
    for (int i = 0; i < 4; ++i)
        lab[i] = *(const int4*)(labels + chunk + (i * TPB + t) * 4);
    float4 r2v[4];
#pragma unroll
    for (int i = 0; i < 4; ++i)
        r2v[i] = *(const float4*)(r2g + chunk + (i * TPB + t) * 4);
    uint2 u[2][4];
#pragma unroll
    for (int i = 0; i < 4; ++i)
        u[0][i] = *(const uint2*)(xbg + (chunk >> 1) + (i * TPB + t) * 2);

    if (t < KC) {
        float cn = 0.f;
#pragma unroll
        for (int r = 0; r < SL; ++r) cn += g_cnt[r * (B * KC) + b * KC + t];
        s_ic[t] = 1.f / cn;
    }
    __syncthreads();
    for (int i = t; i < KC * D; i += TPB) {
        int c = i >> 4, dd = i & 15;
        float s = 0.f;
#pragma unroll
        for (int r = 0; r < SL; ++r) s += g_sums[r * (B * KC * D) + b * (KC * D) + i];
        s_c[c * 17 + dd] = s * s_ic[c];
    }
    __syncthreads();
    if (t < KC) {
        float q = 0.f;
#pragma unroll
        for (int dd = 0; dd < D; ++dd) q = fmaf(s_c[t * 17 + dd], s_c[t * 17 + dd], q);
        s_c2[t] = q;
    }
    __syncthreads();

    float dot[16];
#pragma unroll
    for (int p = 0; p < 16; ++p) dot[p] = 0.f;

#pragma unroll
    for (int d = 0; d < D; ++d) {
        if (d + 1 < D) {
#pragma unroll
            for (int i = 0; i < 4; ++i)
                u[(d + 1) & 1][i] = *(const uint2*)(xbg + (size_t)(d + 1) * (B * N / 2) +
                                                    (chunk >> 1) + (i * TPB + t) * 2);
        }
#pragma unroll
        for (int i = 0; i < 4; ++i) {
            const uint2 c = u[d & 1][i];
            dot[i * 4 + 0] = fmaf(blo(c.x), s_c[lab[i].x * 17 + d], dot[i * 4 + 0]);
            dot[i * 4 + 1] = fmaf(bhi(c.x), s_c[lab[i].y * 17 + d], dot[i * 4 + 1]);
            dot[i * 4 + 2] = fmaf(blo(c.y), s_c[lab[i].z * 17 + d], dot[i * 4 + 2]);
            dot[i * 4 + 3] = fmaf(bhi(c.y), s_c[lab[i].w * 17 + d], dot[i * 4 + 3]);
        }
    }

    float hsum = 0.f;
#pragma unroll
    for (int i = 0; i < 4; ++i) {
        float q, h;
        q = fmaxf(fmaf(-2.f, dot[i * 4 + 0], r2v[i].x) + s_c2[lab[i].x], 0.f);
        h = fmaxf(sqrtf(q) - DELTA_VAR, 0.f); hsum += h * h * s_ic[lab[i].x];
        q = fmaxf(fmaf(-2.f, dot[i * 4 + 1], r2v[i].y) + s_c2[lab[i].y], 0.f);
        h = fmaxf(sqrtf(q) - DELTA_VAR, 0.f); hsum += h * h * s_ic[lab[i].y];
        q = fmaxf(fmaf(-2.f, dot[i * 4 + 2], r2v[i].z) + s_c2[lab[i].z], 0.f);
        h = fmaxf(sqrtf(q) - DELTA_VAR, 0.f); hsum += h * h * s_ic[lab[i].z];
        q = fmaxf(fmaf(-2.f, dot[i * 4 + 3], r2v[i].w) + s_c2[lab[i].w], 0.f);
        h = fmaxf(sqrtf(q) - DELTA_VAR, 0.f); hsum += h * h * s_ic[lab[i].w];
    }
    for (int o = 32; o > 0; o >>= 1) hsum += __shfl_down(hsum, o, 64);
    if ((t & 63) == 0) s_part[t >> 6] = hsum;
    __syncthreads();
    if (t == 0)
        atomicAdd(&g_varp[blockIdx.x & 63],
                  s_part[0] + s_part[1] + s_part[2] + s_part[3]);
}

// ---------------- Fallback pass 2 (R2 k_var): full f32 re-read ----------------
__global__ __launch_bounds__(TPB) void k_var(const float* __restrict__ data,
                                             const int* __restrict__ labels,
                                             float* __restrict__ ws) {
    __shared__ float s_c[KC * 17];
    __shared__ float s_ic[KC];
    __shared__ float s_part[4];
    float* g_sums = ws;
    float* g_cnt  = ws + SL * (B * KC * D);
    float* g_varp = g_cnt + SL * (B * KC);
    const int t = threadIdx.x;
    const int chunk = blockIdx.x * PTS;
    const int b     = chunk >> 19;
    const int n0    = chunk & (N - 1);

    int4 lab[4];
#pragma unroll
    for (int i = 0; i < 4; ++i)
        lab[i] = *(const int4*)(labels + chunk + (i * TPB + t) * 4);

    const float* base = data + (size_t)(b * D) * N + n0;
    float4 v[2][4];
#pragma unroll
    for (int i = 0; i < 4; ++i)
        v[0][i] = *(const float4*)(base + (i * TPB + t) * 4);

    if (t < KC) {
        float cn = 0.f;
#pragma unroll
        for (int r = 0; r < SL; ++r) cn += g_cnt[r * (B * KC) + b * KC + t];
        s_ic[t] = 1.f / cn;
    }
    __syncthreads();
    for (int i = t; i < KC * D; i += TPB) {
        int c = i >> 4, dd = i & 15;
        float s = 0.f;
#pragma unroll
        for (int r = 0; r < SL; ++r) s += g_sums[r * (B * KC * D) + b * (KC * D) + i];
        s_c[c * 17 + dd] = s * s_ic[c];
    }
    __syncthreads();

    float ac[16];
#pragma unroll
    for (int p = 0; p < 16; ++p) ac[p] = 0.f;
#pragma unroll
    for (int d = 0; d < D; ++d) {
        if (d + 1 < D) {
#pragma unroll
            for (int i = 0; i < 4; ++i)
                v[(d + 1) & 1][i] =
                    *(const float4*)(base + (size_t)(d + 1) * N + (i * TPB + t) * 4);
        }
#pragma unroll
        for (int i = 0; i < 4; ++i) {
            const float4 c = v[d & 1][i];
            float df;
            df = c.x - s_c[lab[i].x * 17 + d]; ac[i * 4 + 0] += df * df;
            df = c.y - s_c[lab[i].y * 17 + d]; ac[i * 4 + 1] += df * df;
            df = c.z - s_c[lab[i].z * 17 + d]; ac[i * 4 + 2] += df * df;
            df = c.w - s_c[lab[i].w * 17 + d]; ac[i * 4 + 3] += df * df;
        }
    }
    float hsum = 0.f;
#pragma unroll
    for (int i = 0; i < 4; ++i) {
        float h;
        h = fmaxf(sqrtf(ac[i * 4 + 0]) - DELTA_VAR, 0.f); hsum += h * h * s_ic[lab[i].x];
        h = fmaxf(sqrtf(ac[i * 4 + 1]) - DELTA_VAR, 0.f); hsum += h * h * s_ic[lab[i].y];
        h = fmaxf(sqrtf(ac[i * 4 + 2]) - DELTA_VAR, 0.f); hsum += h * h * s_ic[lab[i].z];
        h = fmaxf(sqrtf(ac[i * 4 + 3]) - DELTA_VAR, 0.f); hsum += h * h * s_ic[lab[i].w];
    }
    for (int o = 32; o > 0; o >>= 1) hsum += __shfl_down(hsum, o, 64);
    if ((t & 63) == 0) s_part[t >> 6] = hsum;
    __syncthreads();
    if (t == 0)
        atomicAdd(&g_varp[blockIdx.x & 63],
                  s_part[0] + s_part[1] + s_part[2] + s_part[3]);
}

// ---------------- Finalize: var + dist + reg -> scalar ----------------
__global__ __launch_bounds__(128) void k_final(const float* __restrict__ ws,
                                               float* __restrict__ out) {
    const float* g_sums = ws;
    const float* g_cnt  = ws + SL * (B * KC * D);
    const float* g_varp = g_cnt + SL * (B * KC);

    __shared__ float s_c[B * KC * 17];
    __shared__ float s_red[2];
    const int t = threadIdx.x;

    float acc = 0.f;
    if (t < B * KC) {
        float cnt = 0.f;
#pragma unroll
        for (int r = 0; r < SL; ++r) cnt += g_cnt[r * (B * KC) + t];
        float ns = 0.f;
        for (int dd = 0; dd < D; ++dd) {
            float s = 0.f;
#pragma unroll
            for (int r = 0; r < SL; ++r) s += g_sums[r * (B * KC * D) + t * D + dd];
            float c = s / cnt;
            s_c[t * 17 + dd] = c;
            ns += c * c;
        }
        acc = sqrtf(ns) / (float)KC;
    }
    if (t < 64) acc += g_varp[t];
    __syncthreads();

    float dacc = 0.f;  // raw sum over [B,K,K] incl. diagonal (= delta_dist^2 each)
    for (int idx = t; idx < B * KC * KC; idx += 128) {
        int b = idx / (KC * KC);
        int r = idx % (KC * KC);
        int i = r / KC, j = r % KC;
        float hd;
        if (i == j) {
            hd = DELTA_DIST * DELTA_DIST;
        } else {
            const float* ci = &s_c[(b * KC + i) * 17];
            const float* cj = &s_c[(b * KC + j) * 17];
            float sq = 0.f;
            for (int dd = 0; dd < D; ++dd) { float df = ci[dd] - cj[dd]; sq += df * df; }
            float hh = fmaxf(DELTA_DIST - sqrtf(sq), 0.f);
            hd = hh * hh;
        }
        dacc += hd;
    }
    float total = acc + dacc / (2.f * KC * (KC - 1));

    for (int o = 32; o > 0; o >>= 1) total += __shfl_down(total, o, 64);
    if ((t & 63) == 0) s_red[t >> 6] = total;
    __syncthreads();
    if (t == 0) out[0] = (s_red[0] + s_red[1]) / (float)B;
}

extern "C" void kernel_launch(void* const* d_in, const int* in_sizes, int n_in,
                              void* d_out, int out_size, void* d_ws, size_t ws_size,
                              hipStream_t stream) {
    const float* data  = (const float*)d_in[0];
    const int* labels  = (const int*)d_in[1];
    float* ws          = (float*)d_ws;

    hipMemsetAsync(d_ws, 0, SMALL * sizeof(float), stream);
    if (ws_size >= NEED) {
        k_p1<<<NBLK, TPB, 0, stream>>>(data, labels, ws);   // writes bf16+r2 handoff
        k_p2<<<NBLK, TPB, 0, stream>>>(labels, ws);         // 80 MB read instead of 142 MB
    } else {
        k_sums<<<NBLK, TPB, 0, stream>>>(data, labels, ws); // no handoff writes
        k_var <<<NBLK, TPB, 0, stream>>>(data, labels, ws); // full f32 re-read (R2 path)
    }
    k_final<<<1, 128, 0, stream>>>(ws, (float*)d_out);
}